// Round 1
// baseline (117.849 us; speedup 1.0000x reference)
//
#include <hip/hip_runtime.h>

typedef _Float16 half4 __attribute__((ext_vector_type(4)));
typedef float floatx4 __attribute__((ext_vector_type(4)));

static constexpr int HW  = 128;  // H == W == 128
static constexpr int DD  = 64;   // D
static constexpr int PST = 132;  // padded LDS stride (halves) for P rows  (128+4 -> conflict-free b64 reads)
static constexpr int VST = 132;  // padded LDS stride (halves) for V^T rows

// One block handles one (b, r) [X-part] or one (b, c) [Y-part]:
//   P = softmax_k(atten[row, k] - shift*(k - row)^2)   (128x128, f16 in LDS)
//   OUT = P @ V                                        (128x128 @ 128x64 via mfma 16x16x16 f16)
// X writes out, Y does out += (disjoint ownership per block, ordered by stream).
template<bool IS_Y>
__global__ __launch_bounds__(256)
void axial_attn(const float* __restrict__ atten,
                const float* __restrict__ vsrc,
                const float* __restrict__ shift_p,
                float* __restrict__ out)
{
    __shared__ _Float16 P [HW * PST];
    __shared__ _Float16 VT[DD * VST];

    const int blk  = blockIdx.x;      // b*128 + r (X)  |  b*128 + c (Y)
    const int b    = blk >> 7;
    const int rc   = blk & 127;
    const int tid  = threadIdx.x;
    const int w    = tid >> 6;
    const int lane = tid & 63;
    const float shift = shift_p[0];   // bias cancels in softmax -> dropped

    // ---- Phase 1: wave-parallel row softmax ----
    const float* ab = atten + (size_t)blk * (HW * HW);
    for (int row = w; row < HW; row += 4) {
        const float a0 = ab[row * HW + lane];
        const float a1 = ab[row * HW + 64 + lane];
        const float d0 = (float)(lane - row);
        const float d1 = (float)(lane + 64 - row);
        float l0 = fmaf(-shift * d0, d0, a0);
        float l1 = fmaf(-shift * d1, d1, a1);
        float m = fmaxf(l0, l1);
        #pragma unroll
        for (int s = 32; s; s >>= 1) m = fmaxf(m, __shfl_xor(m, s));
        const float e0 = __expf(l0 - m);
        const float e1 = __expf(l1 - m);
        float ssum = e0 + e1;
        #pragma unroll
        for (int s = 32; s; s >>= 1) ssum += __shfl_xor(ssum, s);
        const float inv = 1.0f / ssum;   // ssum >= 1 (max element contributes exp(0)=1)
        P[row * PST + lane]      = (_Float16)(e0 * inv);
        P[row * PST + 64 + lane] = (_Float16)(e1 * inv);
    }

    // ---- Phase 2: stage V^T (f16) into LDS: VT[d][k] = v[k][d] ----
    if (!IS_Y) {
        const float* vb = vsrc + (size_t)blk * (HW * DD);   // v[b, r, k, d], contiguous
        #pragma unroll 4
        for (int p = 0; p < 32; ++p) {
            const int e = p * 256 + tid;
            const int k = e >> 6, d = e & 63;
            VT[d * VST + k] = (_Float16)vb[e];
        }
    } else {
        const float* vb = vsrc + ((size_t)b * (HW * HW) + rc) * DD;  // v[b, k, c, d]: stride 8192 over k
        #pragma unroll 4
        for (int p = 0; p < 32; ++p) {
            const int e = p * 256 + tid;
            const int k = e >> 6, d = e & 63;
            VT[d * VST + k] = (_Float16)vb[(size_t)k * (HW * DD) + d];
        }
    }
    __syncthreads();

    // ---- Phase 3: per wave, 32 rows x 64 cols of OUT = P @ V ----
    // mfma_f32_16x16x16f16 layouts (documented + m89-consistent):
    //   A: row = lane&15, k = (lane>>4)*4 + i      B: col = lane&15, same k
    //   D: col = lane&15, row = (lane>>4)*4 + i
    floatx4 acc[2][4] = {};
    const int rbase = 32 * w;
    const int lrow  = lane & 15;
    const int kgrp  = (lane >> 4) * 4;
    for (int k0 = 0; k0 < HW; k0 += 16) {
        const int koff = k0 + kgrp;
        half4 afr[2], bfr[4];
        #pragma unroll
        for (int tr = 0; tr < 2; ++tr)
            afr[tr] = *(const half4*)&P[(rbase + 16 * tr + lrow) * PST + koff];
        #pragma unroll
        for (int tc = 0; tc < 4; ++tc)
            bfr[tc] = *(const half4*)&VT[(16 * tc + lrow) * VST + koff];
        #pragma unroll
        for (int tr = 0; tr < 2; ++tr) {
            #pragma unroll
            for (int tc = 0; tc < 4; ++tc)
                acc[tr][tc] = __builtin_amdgcn_mfma_f32_16x16x16f16(afr[tr], bfr[tc], acc[tr][tc], 0, 0, 0);
        }
    }

    // ---- Phase 4: store ----
    #pragma unroll
    for (int tr = 0; tr < 2; ++tr) {
        #pragma unroll
        for (int tc = 0; tc < 4; ++tc) {
            #pragma unroll
            for (int i = 0; i < 4; ++i) {
                const int row = rbase + 16 * tr + kgrp + i;
                const int col = 16 * tc + lrow;
                if (!IS_Y) {
                    out[(size_t)blk * (HW * DD) + row * DD + col] = acc[tr][tc][i];
                } else {
                    const size_t idx = (size_t)b * (size_t)(HW * HW * DD)
                                     + (size_t)row * (HW * DD) + rc * DD + col;
                    out[idx] += acc[tr][tc][i];
                }
            }
        }
    }
}

extern "C" void kernel_launch(void* const* d_in, const int* in_sizes, int n_in,
                              void* d_out, int out_size, void* d_ws, size_t ws_size,
                              hipStream_t stream)
{
    // inputs: 0=x (unused), 1=atten_x_full, 2=atten_y_full, 3=value_full, 4=shift, 5=bias (cancels)
    const float* atx   = (const float*)d_in[1];
    const float* aty   = (const float*)d_in[2];
    const float* val   = (const float*)d_in[3];
    const float* shift = (const float*)d_in[4];
    float* out = (float*)d_out;

    axial_attn<false><<<dim3(8 * 128), dim3(256), 0, stream>>>(atx, val, shift, out);
    axial_attn<true ><<<dim3(8 * 128), dim3(256), 0, stream>>>(aty, val, shift, out);
}

// Round 2
// 76.968 us; speedup vs baseline: 1.5311x; 1.5311x over previous
//
#include <hip/hip_runtime.h>

typedef _Float16 half4_t __attribute__((ext_vector_type(4)));
typedef float floatx4 __attribute__((ext_vector_type(4)));

static constexpr int HW  = 128;  // H == W == 128
static constexpr int DD  = 64;   // D
static constexpr int RPB = 32;   // output rows per block (quarter of 128)
static constexpr int PST = 132;  // padded LDS stride (halves) for P rows
static constexpr int VST = 132;  // padded LDS stride (halves) for V^T rows

// Block = (b, rc, quarter q): computes 32 output rows of OUT = softmax(logits) @ V
// X: brc=(b,r), P rows are c (softmax over j), V = v[b,r,:,:] contiguous.
// Y: brc=(b,c), P rows are r (softmax over i), V = v[b,:,c,:] strided; out +=.
template<bool IS_Y>
__global__ __launch_bounds__(256)
void axial_attn(const float* __restrict__ atten,
                const float* __restrict__ vsrc,
                const float* __restrict__ shift_p,
                float* __restrict__ out)
{
    __shared__ _Float16 P [RPB * PST];
    __shared__ _Float16 VT[DD * VST];

    const int blk   = blockIdx.x;
    const int q     = blk & 3;          // quarter (consecutive blocks share brc -> L2 reuse)
    const int brc   = blk >> 2;
    const int b     = brc >> 7;
    const int rc    = brc & 127;
    const int rbase = q * RPB;
    const int tid   = threadIdx.x;
    const int w     = tid >> 6;
    const int lane  = tid & 63;
    const float shift = shift_p[0];     // bias cancels in softmax

    // ---- Phase 1: softmax of 32 rows; 2 rows per wave-iter, 32 lanes/row ----
    {
        const float* ab = atten + (size_t)brc * (HW * HW) + (size_t)rbase * HW;
        const int half32 = lane >> 5;
        const int j0     = (lane & 31) * 4;
        #pragma unroll
        for (int it = 0; it < 4; ++it) {
            const int lrow = it * 8 + w * 2 + half32;
            const int grow = rbase + lrow;
            const floatx4 a = *(const floatx4*)&ab[lrow * HW + j0];
            float l[4];
            #pragma unroll
            for (int t = 0; t < 4; ++t) {
                const float d = (float)(j0 + t - grow);
                l[t] = fmaf(-shift * d, d, a[t]);
            }
            float m = fmaxf(fmaxf(l[0], l[1]), fmaxf(l[2], l[3]));
            #pragma unroll
            for (int s = 16; s; s >>= 1) m = fmaxf(m, __shfl_xor(m, s));
            float e[4];
            float ssum = 0.f;
            #pragma unroll
            for (int t = 0; t < 4; ++t) { e[t] = __expf(l[t] - m); ssum += e[t]; }
            #pragma unroll
            for (int s = 16; s; s >>= 1) ssum += __shfl_xor(ssum, s);
            const float inv = 1.0f / ssum;
            half4_t ph;
            #pragma unroll
            for (int t = 0; t < 4; ++t) ph[t] = (_Float16)(e[t] * inv);
            *(half4_t*)&P[lrow * PST + j0] = ph;
        }
    }

    // ---- Phase 2: stage V^T (f16): VT[d][k] = v[k][d], float4 global loads ----
    if (!IS_Y) {
        const float* vb = vsrc + (size_t)brc * (HW * DD);    // contiguous [k][d]
        #pragma unroll
        for (int p = 0; p < 8; ++p) {
            const int e  = p * 256 + tid;      // float4 index (2048 total)
            const int k  = e >> 4;
            const int d4 = (e & 15) * 4;
            const floatx4 v = *(const floatx4*)&vb[e * 4];
            #pragma unroll
            for (int t = 0; t < 4; ++t) VT[(d4 + t) * VST + k] = (_Float16)v[t];
        }
    } else {
        const float* vb = vsrc + ((size_t)b * (HW * HW) + rc) * DD;  // [k][d], k-stride 8192
        #pragma unroll
        for (int p = 0; p < 8; ++p) {
            const int e  = p * 256 + tid;
            const int k  = e >> 4;
            const int d4 = (e & 15) * 4;
            const floatx4 v = *(const floatx4*)&vb[(size_t)k * (HW * DD) + d4];
            #pragma unroll
            for (int t = 0; t < 4; ++t) VT[(d4 + t) * VST + k] = (_Float16)v[t];
        }
    }
    __syncthreads();

    // ---- Phase 3: wave w -> cols [16w,16w+16), local rows 0..31 (2 tiles) ----
    // mfma_f32_16x16x16f16: A[row=lane&15][k=kgrp+i], B[k=kgrp+i][col=lane&15],
    //                       D[col=lane&15][row=kgrp+i]
    const int lrow16 = lane & 15;
    const int kgrp   = (lane >> 4) * 4;
    const int col    = 16 * w + lrow16;
    floatx4 acc[2];
    if (IS_Y) {
        #pragma unroll
        for (int tr = 0; tr < 2; ++tr)
            #pragma unroll
            for (int i = 0; i < 4; ++i) {
                const int orow = rbase + 16 * tr + kgrp + i;
                acc[tr][i] = out[(size_t)b * (HW * HW * DD)
                                 + (size_t)orow * (HW * DD) + rc * DD + col];
            }
    } else {
        acc[0] = (floatx4)(0.f);
        acc[1] = (floatx4)(0.f);
    }
    #pragma unroll
    for (int k0 = 0; k0 < HW; k0 += 16) {
        const int koff = k0 + kgrp;
        const half4_t bfr = *(const half4_t*)&VT[col * VST + koff];
        #pragma unroll
        for (int tr = 0; tr < 2; ++tr) {
            const half4_t afr = *(const half4_t*)&P[(16 * tr + lrow16) * PST + koff];
            acc[tr] = __builtin_amdgcn_mfma_f32_16x16x16f16(afr, bfr, acc[tr], 0, 0, 0);
        }
    }

    // ---- Phase 4: store ----
    #pragma unroll
    for (int tr = 0; tr < 2; ++tr) {
        #pragma unroll
        for (int i = 0; i < 4; ++i) {
            const int orow = rbase + 16 * tr + kgrp + i;
            if (!IS_Y) {
                out[(size_t)brc * (HW * DD) + orow * DD + col] = acc[tr][i];
            } else {
                out[(size_t)b * (HW * HW * DD)
                    + (size_t)orow * (HW * DD) + rc * DD + col] = acc[tr][i];
            }
        }
    }
}

extern "C" void kernel_launch(void* const* d_in, const int* in_sizes, int n_in,
                              void* d_out, int out_size, void* d_ws, size_t ws_size,
                              hipStream_t stream)
{
    // inputs: 0=x (unused), 1=atten_x_full, 2=atten_y_full, 3=value_full, 4=shift, 5=bias (cancels)
    const float* atx   = (const float*)d_in[1];
    const float* aty   = (const float*)d_in[2];
    const float* val   = (const float*)d_in[3];
    const float* shift = (const float*)d_in[4];
    float* out = (float*)d_out;

    axial_attn<false><<<dim3(8 * 128 * 4), dim3(256), 0, stream>>>(atx, val, shift, out);
    axial_attn<true ><<<dim3(8 * 128 * 4), dim3(256), 0, stream>>>(aty, val, shift, out);
}

// Round 3
// 75.525 us; speedup vs baseline: 1.5604x; 1.0191x over previous
//
#include <hip/hip_runtime.h>

typedef _Float16 half4_t __attribute__((ext_vector_type(4)));
typedef _Float16 half8_t __attribute__((ext_vector_type(8)));
typedef float floatx4 __attribute__((ext_vector_type(4)));

static constexpr int HW  = 128;  // H == W == 128
static constexpr int DD  = 64;   // D
static constexpr int RPB = 32;   // output rows per block
static constexpr int PST = 136;  // P row stride in halves (272 B -> 16B-aligned rows)

// Block = (b, rc, quarter q): 32 output rows of OUT = softmax(logits) @ V.
// X: brc=(b,r), softmax over j, V = v[b,r,:,:] (k-stride 64).
// Y: brc=(b,c), softmax over i, V = v[b,:,c,:] (k-stride 8192); out += (preloaded into acc).
// V never touches LDS: each lane loads its mfma B-fragment elements straight
// from global into regs at entry (f32), converts to f16 after the barrier.
template<bool IS_Y>
__global__ __launch_bounds__(256, 4)
void axial_attn(const float* __restrict__ atten,
                const float* __restrict__ vsrc,
                const float* __restrict__ shift_p,
                float* __restrict__ out)
{
    __shared__ _Float16 P[RPB * PST];

    const int blk   = blockIdx.x;
    const int q     = blk & 3;          // quarters adjacent -> L2/L3 reuse of V
    const int brc   = blk >> 2;
    const int b     = brc >> 7;
    const int rc    = brc & 127;
    const int rbase = q * RPB;
    const int tid   = threadIdx.x;
    const int w     = tid >> 6;
    const int lane  = tid & 63;

    const int lrow16 = lane & 15;
    const int g      = lane >> 4;        // 0..3
    const int kgrp   = g * 4;            // mfma k-group base
    const int col    = 16 * w + lrow16;  // d index, wave w owns cols [16w,16w+16)

    // ---- prefetch: V B-fragment elements (32 dwords/lane, 64B-coalesced) ----
    const float* vb = IS_Y
        ? vsrc + (size_t)b * (HW * HW * DD) + (size_t)rc * DD
        : vsrc + (size_t)brc * (HW * DD);
    const int vstride = IS_Y ? HW * DD : DD;
    float vreg[32];
    #pragma unroll
    for (int t = 0; t < 8; ++t)
        #pragma unroll
        for (int i = 0; i < 4; ++i)
            vreg[t * 4 + i] = vb[(size_t)(t * 16 + kgrp + i) * vstride + col];

    // ---- prefetch: atten rows (16-lane rows, 8 elems/lane, 2 iters) ----
    const float* ab = atten + (size_t)brc * (HW * HW) + (size_t)rbase * HW;
    const int j0 = lrow16 * 8;
    floatx4 areg[2][2];
    #pragma unroll
    for (int it = 0; it < 2; ++it) {
        const int lrow = it * 16 + w * 4 + g;
        areg[it][0] = *(const floatx4*)&ab[lrow * HW + j0];
        areg[it][1] = *(const floatx4*)&ab[lrow * HW + j0 + 4];
    }

    // ---- prefetch: Y out-preload straight into the accumulator ----
    floatx4 acc[2];
    if (IS_Y) {
        #pragma unroll
        for (int tr = 0; tr < 2; ++tr)
            #pragma unroll
            for (int i = 0; i < 4; ++i) {
                const int orow = rbase + 16 * tr + kgrp + i;
                acc[tr][i] = out[(size_t)b * (HW * HW * DD)
                                 + (size_t)orow * (HW * DD) + rc * DD + col];
            }
    } else {
        acc[0] = (floatx4)(0.f);
        acc[1] = (floatx4)(0.f);
    }

    const float shift = shift_p[0];      // bias cancels in softmax

    // ---- softmax: 2 iters x (16-lane row, 8 elems/lane) ----
    #pragma unroll
    for (int it = 0; it < 2; ++it) {
        const int lrow = it * 16 + w * 4 + g;
        const int grow = rbase + lrow;
        float l[8];
        #pragma unroll
        for (int t = 0; t < 8; ++t) {
            const float a = (t < 4) ? areg[it][0][t] : areg[it][1][t - 4];
            const float d = (float)(j0 + t - grow);
            l[t] = fmaf(-shift * d, d, a);
        }
        float m = fmaxf(fmaxf(fmaxf(l[0], l[1]), fmaxf(l[2], l[3])),
                        fmaxf(fmaxf(l[4], l[5]), fmaxf(l[6], l[7])));
        #pragma unroll
        for (int s = 8; s; s >>= 1) m = fmaxf(m, __shfl_xor(m, s));
        float e[8], ssum = 0.f;
        #pragma unroll
        for (int t = 0; t < 8; ++t) { e[t] = __expf(l[t] - m); ssum += e[t]; }
        #pragma unroll
        for (int s = 8; s; s >>= 1) ssum += __shfl_xor(ssum, s);
        const float inv = 1.0f / ssum;
        half8_t ph;
        #pragma unroll
        for (int t = 0; t < 8; ++t) ph[t] = (_Float16)(e[t] * inv);
        *(half8_t*)&P[lrow * PST + j0] = ph;   // aligned 16B store
    }
    __syncthreads();

    // ---- convert prefetched V to f16 fragments ----
    half4_t bfr[8];
    #pragma unroll
    for (int t = 0; t < 8; ++t)
        #pragma unroll
        for (int i = 0; i < 4; ++i)
            bfr[t][i] = (_Float16)vreg[t * 4 + i];

    // ---- MFMA: mfma_f32_16x16x16f16, A[row=lane&15][k=kgrp+i], B[k][col=lane&15] ----
    #pragma unroll
    for (int t = 0; t < 8; ++t) {
        const int koff = t * 16 + kgrp;
        #pragma unroll
        for (int tr = 0; tr < 2; ++tr) {
            const half4_t afr = *(const half4_t*)&P[(16 * tr + lrow16) * PST + koff];
            acc[tr] = __builtin_amdgcn_mfma_f32_16x16x16f16(afr, bfr[t], acc[tr], 0, 0, 0);
        }
    }

    // ---- store: D[col=lane&15][row=kgrp+i] ----
    #pragma unroll
    for (int tr = 0; tr < 2; ++tr) {
        #pragma unroll
        for (int i = 0; i < 4; ++i) {
            const int orow = rbase + 16 * tr + kgrp + i;
            if (!IS_Y) {
                out[(size_t)brc * (HW * DD) + orow * DD + col] = acc[tr][i];
            } else {
                out[(size_t)b * (HW * HW * DD)
                    + (size_t)orow * (HW * DD) + rc * DD + col] = acc[tr][i];
            }
        }
    }
}

extern "C" void kernel_launch(void* const* d_in, const int* in_sizes, int n_in,
                              void* d_out, int out_size, void* d_ws, size_t ws_size,
                              hipStream_t stream)
{
    // inputs: 0=x (unused), 1=atten_x_full, 2=atten_y_full, 3=value_full, 4=shift, 5=bias (cancels)
    const float* atx   = (const float*)d_in[1];
    const float* aty   = (const float*)d_in[2];
    const float* val   = (const float*)d_in[3];
    const float* shift = (const float*)d_in[4];
    float* out = (float*)d_out;

    axial_attn<false><<<dim3(8 * 128 * 4), dim3(256), 0, stream>>>(atx, val, shift, out);
    axial_attn<true ><<<dim3(8 * 128 * 4), dim3(256), 0, stream>>>(aty, val, shift, out);
}